// Round 2
// baseline (29.095 us; speedup 1.0000x reference)
//
#include <hip/hip_runtime.h>

// GCNConv, full upper-tri graph + self loops, B=512, N=64, C=O=256.
// out[b,i,:] = relu( (1/sqrt(i+1)) * sum_{j<=i} (X[b]W)[j,:]/sqrt(j+1) + bias )
//
// R2: 2 graphs per block (grid 256), double-buffered LDS, W fragments held in
// registers for the whole block, g1 global loads overlapped with g0 compute.

#define BATCH 512
#define NNODE 64
#define CIN   256
#define COUT  256

typedef __bf16 bf16x8 __attribute__((ext_vector_type(8)));
typedef float  f32x4  __attribute__((ext_vector_type(4)));

__device__ __forceinline__ unsigned int f2bf_bits(float f) {
    unsigned int u = __builtin_bit_cast(unsigned int, f);
    return (u + 0x7fffu + ((u >> 16) & 1u)) >> 16;
}

__global__ __launch_bounds__(256, 1) void gcn_fused(
    const float* __restrict__ X,
    const unsigned short* __restrict__ WT,   // bf16 bits, [COUT][CIN]
    const float* __restrict__ bias,
    float* __restrict__ out)
{
    __shared__ uint4 Xs4[2][2048];           // 2 x 32 KiB, swizzled bf16 X
    const int tid  = threadIdx.x;
    const int lane = tid & 63;
    const int w    = tid >> 6;               // wave: output cols [w*64, w*64+64)
    const int g    = lane >> 4;
    const int c    = lane & 15;
    const int g0   = blockIdx.x * 2;

    const float* xb0 = X + (size_t)g0 * (NNODE * CIN);
    const float* xb1 = xb0 + NNODE * CIN;

    // ---- W fragments: load once, keep in registers for both graphs ----
    bf16x8 bfr[8][4];                        // [kk][nt], 128 VGPRs
    {
        const unsigned short* WTb = WT + (size_t)(w * 64 + c) * CIN + g * 8;
#pragma unroll
        for (int kk = 0; kk < 8; ++kk)
#pragma unroll
            for (int nt = 0; nt < 4; ++nt)
                bfr[kk][nt] = *reinterpret_cast<const bf16x8*>(WTb + nt * 16 * CIN + kk * 32);
    }
    float bias_c[4];
#pragma unroll
    for (int nt = 0; nt < 4; ++nt)
        bias_c[nt] = bias[w * 64 + nt * 16 + c];

    float4 pf[16];                           // staging regs, reused per graph

    // issue g0 loads
#pragma unroll
    for (int i = 0; i < 8; ++i) {
        int ch = tid + i * 256;
        const float4* p = reinterpret_cast<const float4*>(xb0 + (ch >> 5) * CIN + ((ch & 31) << 3));
        pf[2 * i]     = p[0];
        pf[2 * i + 1] = p[1];
    }
    // convert + swizzled ds_write into buf0
#pragma unroll
    for (int i = 0; i < 8; ++i) {
        int ch  = tid + i * 256;
        int row = ch >> 5;
        int c8  = (ch & 31) << 3;
        float4 v0 = pf[2 * i], v1 = pf[2 * i + 1];
        unsigned int w0 = f2bf_bits(v0.x) | (f2bf_bits(v0.y) << 16);
        unsigned int w1 = f2bf_bits(v0.z) | (f2bf_bits(v0.w) << 16);
        unsigned int w2 = f2bf_bits(v1.x) | (f2bf_bits(v1.y) << 16);
        unsigned int w3 = f2bf_bits(v1.z) | (f2bf_bits(v1.w) << 16);
        int byte = (row << 9) + (c8 << 1);
        byte ^= (row & 7) << 4;
        *reinterpret_cast<uint4*>((unsigned char*)Xs4[0] + byte) = make_uint4(w0, w1, w2, w3);
    }
    // issue g1 loads (in flight across g0 compute)
#pragma unroll
    for (int i = 0; i < 8; ++i) {
        int ch = tid + i * 256;
        const float4* p = reinterpret_cast<const float4*>(xb1 + (ch >> 5) * CIN + ((ch & 31) << 3));
        pf[2 * i]     = p[0];
        pf[2 * i + 1] = p[1];
    }

    // ---- per-graph compute: GEMM + scaled prefix scan + bias/relu/store ----
    auto compute_graph = [&](const unsigned char* Xs, float* ob) {
        f32x4 acc[4][4] = {};
        const int swz = (c & 7) << 4;
#pragma unroll
        for (int kk = 0; kk < 8; ++kk) {
            bf16x8 a[4];
#pragma unroll
            for (int mt = 0; mt < 4; ++mt) {
                int byte = ((mt * 16 + c) << 9) + (kk << 6) + (g << 4);
                byte ^= swz;
                a[mt] = *reinterpret_cast<const bf16x8*>(Xs + byte);
            }
#pragma unroll
            for (int mt = 0; mt < 4; ++mt)
#pragma unroll
                for (int nt = 0; nt < 4; ++nt)
                    acc[mt][nt] = __builtin_amdgcn_mfma_f32_16x16x32_bf16(
                        a[mt], bfr[kk][nt], acc[mt][nt], 0, 0, 0);
        }
        // per-lane inclusive scan within each 4-row chunk
        float t[4][4];
#pragma unroll
        for (int mt = 0; mt < 4; ++mt) {
            const int rbase = mt * 16 + g * 4;
            float d0 = rsqrtf((float)(rbase + 1));
            float d1 = rsqrtf((float)(rbase + 2));
            float d2 = rsqrtf((float)(rbase + 3));
            float d3 = rsqrtf((float)(rbase + 4));
#pragma unroll
            for (int nt = 0; nt < 4; ++nt) {
                f32x4 v = acc[mt][nt];
                v[0] *= d0; v[1] *= d1; v[2] *= d2; v[3] *= d3;
                v[1] += v[0]; v[2] += v[1]; v[3] += v[2];
                acc[mt][nt] = v;
                t[mt][nt] = v[3];
            }
        }
        // cross-chunk exclusive scan (16 chunks) via shfl
        float O[4][4];                       // [nt][mt]
#pragma unroll
        for (int nt = 0; nt < 4; ++nt) {
            float S = 0.0f;
#pragma unroll
            for (int q = 0; q < 16; ++q) {
                const int mtq = q >> 2, gq = q & 3;
                float v = __shfl(t[mtq][nt], c + (gq << 4), 64);
                if (gq == g) O[nt][mtq] = S;
                S += v;
            }
        }
#pragma unroll
        for (int mt = 0; mt < 4; ++mt) {
#pragma unroll
            for (int r = 0; r < 4; ++r) {
                const int row = mt * 16 + g * 4 + r;
                float dr = rsqrtf((float)(row + 1));
#pragma unroll
                for (int nt = 0; nt < 4; ++nt) {
                    float val = (acc[mt][nt][r] + O[nt][mt]) * dr + bias_c[nt];
                    ob[row * COUT + nt * 16] = fmaxf(val, 0.0f);
                }
            }
        }
    };

    __syncthreads();
    compute_graph((const unsigned char*)Xs4[0],
                  out + (size_t)g0 * (NNODE * COUT) + (w * 64 + c));

    // convert + write buf1 (g1 loads have been in flight during g0 compute)
#pragma unroll
    for (int i = 0; i < 8; ++i) {
        int ch  = tid + i * 256;
        int row = ch >> 5;
        int c8  = (ch & 31) << 3;
        float4 v0 = pf[2 * i], v1 = pf[2 * i + 1];
        unsigned int w0 = f2bf_bits(v0.x) | (f2bf_bits(v0.y) << 16);
        unsigned int w1 = f2bf_bits(v0.z) | (f2bf_bits(v0.w) << 16);
        unsigned int w2 = f2bf_bits(v1.x) | (f2bf_bits(v1.y) << 16);
        unsigned int w3 = f2bf_bits(v1.z) | (f2bf_bits(v1.w) << 16);
        int byte = (row << 9) + (c8 << 1);
        byte ^= (row & 7) << 4;
        *reinterpret_cast<uint4*>((unsigned char*)Xs4[1] + byte) = make_uint4(w0, w1, w2, w3);
    }
    __syncthreads();
    compute_graph((const unsigned char*)Xs4[1],
                  out + (size_t)(g0 + 1) * (NNODE * COUT) + (w * 64 + c));
}

// W (f32, [K=256][N=256]) -> Wt (bf16 bits, [N=256][K=256])
__global__ void wprep(const float* __restrict__ W, unsigned short* __restrict__ Wt) {
    __shared__ unsigned short tile[64][72];
    const int tid = threadIdx.x;
    const int tk  = blockIdx.x & 3;
    const int tn  = blockIdx.x >> 2;
#pragma unroll
    for (int i = 0; i < 16; ++i) {
        int idx = tid + i * 256;
        int r  = idx >> 6;
        int cc = idx & 63;
        tile[cc][r] = (unsigned short)f2bf_bits(W[(tk * 64 + r) * 256 + tn * 64 + cc]);
    }
    __syncthreads();
#pragma unroll
    for (int i = 0; i < 16; ++i) {
        int idx = tid + i * 256;
        int rr = idx >> 6;
        int cc = idx & 63;
        Wt[(tn * 64 + rr) * 256 + tk * 64 + cc] = tile[rr][cc];
    }
}

extern "C" void kernel_launch(void* const* d_in, const int* in_sizes, int n_in,
                              void* d_out, int out_size, void* d_ws, size_t ws_size,
                              hipStream_t stream) {
    const float* x = (const float*)d_in[0];
    const float* W = (const float*)d_in[1];
    const float* b = (const float*)d_in[2];
    float* out = (float*)d_out;
    unsigned short* Wt = (unsigned short*)d_ws;

    hipLaunchKernelGGL(wprep, dim3(16), dim3(256), 0, stream, W, Wt);
    hipLaunchKernelGGL(gcn_fused, dim3(BATCH / 2), dim3(256), 0, stream, x, Wt, b, out);
}